// Round 6
// baseline (132.621 us; speedup 1.0000x reference)
//
#include <hip/hip_runtime.h>
#include <math.h>

#define NROWS 32768
#define NCODE 1024
#define AMB_CAP 8192
#define GAP_THRESH 1.5e-4f  // exact fp32 gap; emulation err ~1e-5, np-ref rounding ~2e-5

typedef __attribute__((ext_vector_type(8))) short bf16x8;   // 8 bf16 = 4 VGPRs
typedef __attribute__((ext_vector_type(4))) float f32x4;    // MFMA acc

__device__ __forceinline__ unsigned short bf16_rne(float f) {
    unsigned u = __float_as_uint(f);
    unsigned r = u + 0x7FFFu + ((u >> 16) & 1u);
    return (unsigned short)(r >> 16);
}

// ---------------------------------------------------------------------------
// prep: cn4 = ||c||^2+4, minK=+inf bits, zero counter/gsumsq/ticket,
// codebook -> frag-major split-bf16 of (-2c) (wsB). 16 blocks x 64 codes.
// B pre-scaled by -2 (exact exponent shift, commutes with bf16 RNE split) so
// vq_main's MFMA chain computes cn4 - 2*x.c with acc initialized to cn4.
// ---------------------------------------------------------------------------
__global__ __launch_bounds__(64) void vq_prep(
    const float* __restrict__ cb, float* __restrict__ cn4,
    unsigned* __restrict__ minK, unsigned* __restrict__ counter,
    float* __restrict__ gsumsq, unsigned* __restrict__ ticket,
    unsigned short* __restrict__ wsB)
{
    int c = blockIdx.x * 64 + threadIdx.x;
    if (c == 0) { *counter = 0u; *gsumsq = 0.f; *ticket = 0u; }
    float v[64];
    const float4* src = (const float4*)(cb + (size_t)c * 64);
    float s = 0.f;
    #pragma unroll
    for (int i = 0; i < 16; i++) {
        float4 t = src[i];
        v[i*4+0] = t.x; v[i*4+1] = t.y; v[i*4+2] = t.z; v[i*4+3] = t.w;
        s += t.x*t.x + t.y*t.y + t.z*t.z + t.w*t.w;
    }
    cn4[c] = s + 4.0f;
    minK[c] = 0x7F800000u;   // +inf bits (full dists >= 0 -> raw-bit order ok)
    int cc = c >> 6, ct = (c >> 4) & 3, cl = c & 15;
    #pragma unroll
    for (int q = 0; q < 4; q++) {
        int half = q & 1, lo = q >> 1;
        #pragma unroll
        for (int g = 0; g < 4; g++) {
            unsigned short u8[8] __attribute__((aligned(16)));
            #pragma unroll
            for (int j = 0; j < 8; j++) {
                float f = -2.0f * v[half*32 + g*8 + j];   // exact scale
                unsigned short h = bf16_rne(f);
                if (lo) h = bf16_rne(f - __uint_as_float((unsigned)h << 16));
                u8[j] = h;
            }
            size_t off = (size_t)cc * 8192 + ct * 2048 + q * 512 + (g * 16 + cl) * 8;
            *(uint4*)(wsB + off) = *(const uint4*)u8;
        }
    }
}

// ---------------------------------------------------------------------------
// main (r19): r18's static 4-slot pipeline, but with the register budget
// FORCED via amdgpu_waves_per_eu(4,4). r18's tell: VGPR_Count=64 again --
// the compiler's occupancy heuristic targets 8 waves/EU unless pinned, so
// the 16 named B-slots were never co-resident and every PF sank to its COMP
// (pipeline collapsed back to r15's serial chain). Pinning exactly 4
// waves/EU removes the incentive: 128-VGPR budget, 16 waves/CU (same
// occupancy as the 42-us baselines).
// Also: the per-tile dependent shfl_xor pair (2 x ~120cy lgkmcnt stalls
// inside every tile's chain) is batched -- COMP leaves a named per-tile cm
// (cmA..cmD); FLUSH per 4-tile body issues 4 independent shfl#1s, then 4
// shfl#2s, then 4 guarded atomics (stall amortized 8x120 -> ~2x120 / 4
// tiles). All register indexing compile-time static (rule #20).
// Frame identical to r15: 512 blocks x 512 thr, 8 waves = 4 row-groups x 2
// code-halves, wave = 16 rows x 512 codes = 32 tiles. VALIDITY GATE:
// VGPR_Count >= ~100, no FETCH/WRITE balloon.
// ---------------------------------------------------------------------------
__global__ __attribute__((amdgpu_waves_per_eu(4, 4))) __launch_bounds__(512)
void vq_main(
    const float* __restrict__ x, const float* __restrict__ cb,
    const unsigned short* __restrict__ wsB, const float* __restrict__ cn4,
    float* __restrict__ out, unsigned* __restrict__ minK,
    unsigned* __restrict__ counter, int* __restrict__ amb,
    float* __restrict__ gsumsq)
{
    __shared__ float    cn4L[1024];
    __shared__ unsigned scrE[1024];        // per-block per-code min full dist (raw bits)
    __shared__ float mD1[128], mD2[128];   // [row 0..63][half 0..1]
    __shared__ int   mI1[128];
    __shared__ int   tokS[64];
    __shared__ float redS[8];

    const int tid = threadIdx.x;
    const int lane = tid & 63;
    const int wi = tid >> 6;         // 0..7
    const int g = wi >> 1;           // row group 0..3 (16 rows each)
    const int h = wi & 1;            // code half: codes h*512 .. +511
    const int ln15 = lane & 15;
    const int q = lane >> 4;
    const int row0 = blockIdx.x * 64;

    // stage cn4 (1024 f32) + init scrE
    cn4L[tid]       = cn4[tid];
    cn4L[512 + tid] = cn4[512 + tid];
    scrE[tid]       = 0x7F800000u;
    scrE[512 + tid] = 0x7F800000u;

    // ---- A: 16 rows fp32 -> split-bf16 frags in regs; row norms via shfl ----
    bf16x8 Ah0, Ah1, Al0, Al1;
    float xnm4[4];
    {
        const float* xr = x + (size_t)(row0 + g*16 + ln15) * 64 + q * 8;
        float4 f0 = *(const float4*)xr;
        float4 f1 = *(const float4*)(xr + 4);
        float4 f2 = *(const float4*)(xr + 32);
        float4 f3 = *(const float4*)(xr + 36);
        float fa[8] = {f0.x,f0.y,f0.z,f0.w,f1.x,f1.y,f1.z,f1.w};
        float fb[8] = {f2.x,f2.y,f2.z,f2.w,f3.x,f3.y,f3.z,f3.w};
        unsigned short hh8[8] __attribute__((aligned(16)));
        unsigned short ll8[8] __attribute__((aligned(16)));
        unsigned short h28[8] __attribute__((aligned(16)));
        unsigned short l28[8] __attribute__((aligned(16)));
        float ss = 0.f;
        #pragma unroll
        for (int j = 0; j < 8; j++) {
            ss += fa[j]*fa[j] + fb[j]*fb[j];
            unsigned short hh = bf16_rne(fa[j]);
            hh8[j] = hh; ll8[j] = bf16_rne(fa[j] - __uint_as_float((unsigned)hh << 16));
            hh = bf16_rne(fb[j]);
            h28[j] = hh; l28[j] = bf16_rne(fb[j] - __uint_as_float((unsigned)hh << 16));
        }
        Ah0 = *(const bf16x8*)hh8; Al0 = *(const bf16x8*)ll8;
        Ah1 = *(const bf16x8*)h28; Al1 = *(const bf16x8*)l28;
        ss += __shfl_xor(ss, 16);
        ss += __shfl_xor(ss, 32);            // ||x_row(ln15)||^2
        #pragma unroll
        for (int r = 0; r < 4; r++)
            xnm4[r] = __shfl(ss, (q << 2) | r, 64) - 4.0f;  // xn(row q*4+r) - 4
    }
    __syncthreads();   // cn4L + scrE ready; the only barrier before the epilogue

    float d1[4], d2[4];
    int   i1[4];
    #pragma unroll
    for (int r = 0; r < 4; r++) { d1[r] = INFINITY; d2[r] = INFINITY; i1[r] = 0; }

    // ---- tile loop: 32 tiles of 16 codes, B from L2, static 4-slot pipeline ----
    const char* wsQ = (const char*)wsB + (size_t)h * 131072 + lane * 16;

#define PF(S, T_) { const char* tb_ = wsQ + (T_) * 4096;                        \
        S##h0 = *(const bf16x8*)(tb_);                                          \
        S##h1 = *(const bf16x8*)(tb_ + 1024);                                   \
        S##l0 = *(const bf16x8*)(tb_ + 2048);                                   \
        S##l1 = *(const bf16x8*)(tb_ + 3072); }

#define COMP(S, T_, CM) {                                                       \
        const int kid_ = h*512 + (T_)*16 + ln15;                                \
        const float cn4v_ = cn4L[kid_];                                         \
        f32x4 a0_ = {cn4v_, cn4v_, cn4v_, cn4v_};                               \
        a0_ = __builtin_amdgcn_mfma_f32_16x16x32_bf16(Ah0, S##h0, a0_, 0, 0, 0);\
        a0_ = __builtin_amdgcn_mfma_f32_16x16x32_bf16(Ah1, S##h1, a0_, 0, 0, 0);\
        a0_ = __builtin_amdgcn_mfma_f32_16x16x32_bf16(Ah0, S##l0, a0_, 0, 0, 0);\
        a0_ = __builtin_amdgcn_mfma_f32_16x16x32_bf16(Ah1, S##l1, a0_, 0, 0, 0);\
        a0_ = __builtin_amdgcn_mfma_f32_16x16x32_bf16(Al0, S##h0, a0_, 0, 0, 0);\
        a0_ = __builtin_amdgcn_mfma_f32_16x16x32_bf16(Al1, S##h1, a0_, 0, 0, 0);\
        float cm_ = INFINITY;                                                   \
        _Pragma("unroll")                                                       \
        for (int r_ = 0; r_ < 4; r_++) {                                        \
            float wv = a0_[r_];                                                 \
            d2[r_] = fminf(fmaxf(wv, d1[r_]), d2[r_]);                          \
            bool lt = wv < d1[r_];                                              \
            i1[r_] = lt ? kid_ : i1[r_];                                        \
            d1[r_] = fminf(wv, d1[r_]);                                         \
            cm_ = fminf(cm_, wv + xnm4[r_]);                                    \
        }                                                                       \
        CM = cm_; }

#define FLUSH(TB) {                                                             \
        float sA_ = fminf(cmA, __shfl_xor(cmA, 16));                            \
        float sB_ = fminf(cmB, __shfl_xor(cmB, 16));                            \
        float sC_ = fminf(cmC, __shfl_xor(cmC, 16));                            \
        float sD_ = fminf(cmD, __shfl_xor(cmD, 16));                            \
        sA_ = fminf(sA_, __shfl_xor(sA_, 32));                                  \
        sB_ = fminf(sB_, __shfl_xor(sB_, 32));                                  \
        sC_ = fminf(sC_, __shfl_xor(sC_, 32));                                  \
        sD_ = fminf(sD_, __shfl_xor(sD_, 32));                                  \
        if (q == 0) atomicMin(&scrE[h*512 + ((TB)+0)*16 + ln15], __float_as_uint(sA_)); \
        if (q == 1) atomicMin(&scrE[h*512 + ((TB)+1)*16 + ln15], __float_as_uint(sB_)); \
        if (q == 2) atomicMin(&scrE[h*512 + ((TB)+2)*16 + ln15], __float_as_uint(sC_)); \
        if (q == 3) atomicMin(&scrE[h*512 + ((TB)+3)*16 + ln15], __float_as_uint(sD_)); }

    bf16x8 SAh0,SAh1,SAl0,SAl1, SBh0,SBh1,SBl0,SBl1,
           SCh0,SCh1,SCl0,SCl1, SDh0,SDh1,SDl0,SDl1;
    float cmA, cmB, cmC, cmD;
    PF(SA, 0); PF(SB, 1); PF(SC, 2);
    for (int tb = 0; tb < 28; tb += 4) {
        PF(SD, tb+3); COMP(SA, tb+0, cmA);
        PF(SA, tb+4); COMP(SB, tb+1, cmB);
        PF(SB, tb+5); COMP(SC, tb+2, cmC);
        PF(SC, tb+6); COMP(SD, tb+3, cmD);
        FLUSH(tb);
    }
    PF(SD, 31);
    COMP(SA, 28, cmA); COMP(SB, 29, cmB); COMP(SC, 30, cmC); COMP(SD, 31, cmD);
    FLUSH(28);

#undef PF
#undef COMP
#undef FLUSH

    // ---- butterfly exact top-2 merge across the 16 code-column lanes ----
    #pragma unroll
    for (int d = 1; d < 16; d <<= 1) {
        #pragma unroll
        for (int r = 0; r < 4; r++) {
            float od1 = __shfl_xor(d1[r], d);
            int   oi1 = __shfl_xor(i1[r], d);
            float od2 = __shfl_xor(d2[r], d);
            bool take = (od1 < d1[r]) || (od1 == d1[r] && oi1 < i1[r]);
            float loser = take ? d1[r] : od1;
            d2[r] = fminf(fminf(d2[r], od2), loser);
            d1[r] = take ? od1 : d1[r];
            i1[r] = take ? oi1 : i1[r];
        }
    }
    if (ln15 == 0) {
        #pragma unroll
        for (int r = 0; r < 4; r++) {
            int idx = (g*16 + q*4 + r) * 2 + h;
            mD1[idx] = d1[r]; mI1[idx] = i1[r]; mD2[idx] = d2[r];
        }
    }
    __syncthreads();   // per-half candidates staged; all scrE atomics done

    // ---- exact cross-half merge -> token + ambiguity (1 thread/row) ----
    if (tid < 64) {
        float a1 = mD1[tid*2],   b1 = mD1[tid*2+1];
        int   ai = mI1[tid*2],   bi = mI1[tid*2+1];
        float a2 = mD2[tid*2],   b2 = mD2[tid*2+1];
        bool ta = (a1 < b1) || (a1 == b1 && ai < bi);
        float D1 = ta ? a1 : b1;
        int   I1 = ta ? ai : bi;
        float D2 = ta ? fminf(a2, b1) : fminf(b2, a1);
        tokS[tid] = I1;
        if (D2 - D1 < GAP_THRESH) {
            unsigned idx = atomicAdd(counter, 1u);
            if (idx < AMB_CAP) { amb[2*idx] = row0 + tid; amb[2*idx+1] = I1; }
        }
    }

    // ---- entropy: filtered global atomicMin ----
    {
        unsigned u0 = scrE[tid];
        if (u0 < minK[tid]) atomicMin(&minK[tid], u0);          // race benign: monotone
        unsigned u1 = scrE[512 + tid];
        if (u1 < minK[512 + tid]) atomicMin(&minK[512 + tid], u1);
    }
    __syncthreads();   // tokS ready

    // ---- emb gather + sumsq (512 threads x 2 float4 = 64 rows x 16) ----
    {
        float acc2 = 0.f;
        #pragma unroll
        for (int uu = 0; uu < 2; uu++) {
            int u = uu*512 + tid;
            int row = u >> 4, c4 = u & 15;
            int tok = tokS[row];
            float4 c = ((const float4*)(cb + (size_t)tok*64))[c4];
            float4 xx = ((const float4*)(x + (size_t)(row0 + row)*64))[c4];
            ((float4*)(out + (size_t)(row0 + row)*64))[c4] = c;
            float dx = c.x-xx.x, dy = c.y-xx.y, dz = c.z-xx.z, dw = c.w-xx.w;
            acc2 += dx*dx + dy*dy + dz*dz + dw*dw;
        }
        #pragma unroll
        for (int o = 32; o > 0; o >>= 1) acc2 += __shfl_down(acc2, o);
        if (lane == 0) redS[wi] = acc2;
        __syncthreads();
        if (tid == 0) {
            float t = 0.f;
            #pragma unroll
            for (int w = 0; w < 8; w++) t += redS[w];
            atomicAdd(gsumsq, t);
        }
    }
}

// ---------------------------------------------------------------------------
// tail: 64 blocks. (A) fp64 fixup with cb staged through LDS in 4 coalesced
// 64-KB batches. (B) last-ticket block: sum minK + loss. (unchanged)
// ---------------------------------------------------------------------------
__global__ __launch_bounds__(256) void vq_tail(
    const float* __restrict__ x, const float* __restrict__ cb,
    float* __restrict__ out, const unsigned* __restrict__ counter,
    const int* __restrict__ amb, float* __restrict__ gsumsq,
    unsigned* __restrict__ ticket, const unsigned* __restrict__ minK,
    float* __restrict__ out_loss)
{
    __shared__ __align__(16) float cbS[16384];   // 64 KB: 256 codes x 64 dims
    __shared__ double xs[64];
    __shared__ double bd[256];
    __shared__ int    bi[256];
    __shared__ unsigned lastS;
    __shared__ float redS[4];

    const int tid = threadIdx.x;

    // ---- A: fp64 re-decision for ambiguous rows (coalesced cb staging) ----
    unsigned cnt = *counter; if (cnt > AMB_CAP) cnt = AMB_CAP;
    for (unsigned i = blockIdx.x; i < cnt; i += gridDim.x) {
        int row = amb[2*i], oldk = amb[2*i+1];
        __syncthreads();
        if (tid < 64) xs[tid] = (double)x[(size_t)row*64 + tid];
        __syncthreads();
        double xn = 0.0;
        #pragma unroll 8
        for (int d = 0; d < 64; d++) xn += xs[d]*xs[d];
        double best = INFINITY; int bk = 1 << 30;
        for (int b = 0; b < 4; b++) {           // 256 codes per batch
            __syncthreads();                    // cbS free for reuse
            #pragma unroll
            for (int k = 0; k < 16; k++)        // 64 KB coalesced: 16 float4/thread
                ((float4*)cbS)[k*256 + tid] = ((const float4*)cb)[b*4096 + k*256 + tid];
            __syncthreads();
            int kcode = b*256 + tid;
            const int t6 = tid & 63;
            double dot = 0.0, cn2 = 0.0;
            #pragma unroll 8
            for (int dd = 0; dd < 64; dd++) {
                int d = (dd + t6) & 63;         // rotation: 2 lanes/bank (free)
                double cv = (double)cbS[tid*64 + d];
                dot = fma(xs[d], cv, dot);
                cn2 = fma(cv, cv, cn2);
            }
            double dist = (xn - 2.0*dot) + cn2;
            if (dist < best || (dist == best && kcode < bk)) { best = dist; bk = kcode; }
        }
        bd[tid] = best; bi[tid] = bk;
        __syncthreads();
        for (int s = 128; s > 0; s >>= 1) {
            if (tid < s) {
                double od = bd[tid+s]; int ok = bi[tid+s];
                if (od < bd[tid] || (od == bd[tid] && ok < bi[tid])) { bd[tid] = od; bi[tid] = ok; }
            }
            __syncthreads();
        }
        int bestk = bi[0];
        if (bestk != oldk) {
            double part = 0.0;
            if (tid < 64) {
                float cn = cb[(size_t)bestk*64 + tid];
                float co = cb[(size_t)oldk*64 + tid];
                out[(size_t)row*64 + tid] = cn;
                double dn = (double)cn - xs[tid];
                double dl = (double)co - xs[tid];
                part = dn*dn - dl*dl;
            }
            __syncthreads();
            bd[tid] = part;
            __syncthreads();
            for (int s = 128; s > 0; s >>= 1) {
                if (tid < s) bd[tid] += bd[tid+s];
                __syncthreads();
            }
            if (tid == 0) atomicAdd(gsumsq, (float)bd[0]);
        }
    }

    // ---- B: last block assembles the loss ----
    __syncthreads();
    if (tid == 0) {
        __threadfence();
        lastS = (atomicAdd(ticket, 1u) == 63u) ? 1u : 0u;
    }
    __syncthreads();
    if (lastS) {
        __threadfence();
        float s = 0.f;
        #pragma unroll
        for (int jj = 0; jj < 4; jj++)
            s += __uint_as_float(minK[jj*256 + tid]);   // raw bits of positive dists
        #pragma unroll
        for (int o = 32; o > 0; o >>= 1) s += __shfl_down(s, o);
        if ((tid & 63) == 0) redS[tid >> 6] = s;
        __syncthreads();
        if (tid == 0) {
            float gs = atomicAdd(gsumsq, 0.0f);         // coherent device-scope read
            float tot = redS[0] + redS[1] + redS[2] + redS[3];
            out_loss[0] = 1.25f * (gs / 2097152.0f) + 0.1f * (tot / 1024.0f);
        }
    }
}

extern "C" void kernel_launch(void* const* d_in, const int* in_sizes, int n_in,
                              void* d_out, int out_size, void* d_ws, size_t ws_size,
                              hipStream_t stream) {
    const float* x  = (const float*)d_in[0];   // [32768, 64]
    const float* cb = (const float*)d_in[1];   // [1024, 64]
    float* out = (float*)d_out;                // [0,2097152): emb; [2097152]: loss

    char* ws = (char*)d_ws;
    unsigned*       counter = (unsigned*)ws;                    // @0
    float*          gsumsq  = (float*)(ws + 4);                 // @4
    unsigned*       ticket  = (unsigned*)(ws + 8);              // @8
    float*          cn4     = (float*)(ws + 1024);              // 4 KB
    unsigned*       minK    = (unsigned*)(ws + 8192);           // 4 KB
    int*            amb     = (int*)(ws + 16384);               // 64 KB
    unsigned short* wsB     = (unsigned short*)(ws + 131072);   // 256 KB

    vq_prep<<<16,  64,  0, stream>>>(cb, cn4, minK, counter, gsumsq, ticket, wsB);
    vq_main<<<512, 512, 0, stream>>>(x, cb, wsB, cn4, out, minK, counter, amb, gsumsq);
    vq_tail<<<64,  256, 0, stream>>>(x, cb, out, counter, amb, gsumsq, ticket, minK,
                                     out + 2097152);
}

// Round 7
// 114.876 us; speedup vs baseline: 1.1545x; 1.1545x over previous
//
#include <hip/hip_runtime.h>
#include <math.h>

#define NROWS 32768
#define NCODE 1024
#define AMB_CAP 8192
#define GAP_THRESH 1.5e-4f  // exact fp32 gap; emulation err ~1e-5, np-ref rounding ~2e-5

typedef __attribute__((ext_vector_type(8))) short bf16x8;   // 8 bf16 = 4 VGPRs
typedef __attribute__((ext_vector_type(4))) float f32x4;    // MFMA acc

__device__ __forceinline__ unsigned short bf16_rne(float f) {
    unsigned u = __float_as_uint(f);
    unsigned r = u + 0x7FFFu + ((u >> 16) & 1u);
    return (unsigned short)(r >> 16);
}

// ---------------------------------------------------------------------------
// prep: cn4 = ||c||^2+4, minK=+inf bits, zero counter/gsumsq/ticket,
// codebook -> frag-major split-bf16 of (-2c) (wsB). 16 blocks x 64 codes.
// B pre-scaled by -2 (exact exponent shift, commutes with bf16 RNE split) so
// vq_main's MFMA chain computes cn4 - 2*x.c with acc initialized to cn4.
// ---------------------------------------------------------------------------
__global__ __launch_bounds__(64) void vq_prep(
    const float* __restrict__ cb, float* __restrict__ cn4,
    unsigned* __restrict__ minK, unsigned* __restrict__ counter,
    float* __restrict__ gsumsq, unsigned* __restrict__ ticket,
    unsigned short* __restrict__ wsB)
{
    int c = blockIdx.x * 64 + threadIdx.x;
    if (c == 0) { *counter = 0u; *gsumsq = 0.f; *ticket = 0u; }
    float v[64];
    const float4* src = (const float4*)(cb + (size_t)c * 64);
    float s = 0.f;
    #pragma unroll
    for (int i = 0; i < 16; i++) {
        float4 t = src[i];
        v[i*4+0] = t.x; v[i*4+1] = t.y; v[i*4+2] = t.z; v[i*4+3] = t.w;
        s += t.x*t.x + t.y*t.y + t.z*t.z + t.w*t.w;
    }
    cn4[c] = s + 4.0f;
    minK[c] = 0x7F800000u;   // +inf bits (full dists >= 0 -> raw-bit order ok)
    int cc = c >> 6, ct = (c >> 4) & 3, cl = c & 15;
    #pragma unroll
    for (int q = 0; q < 4; q++) {
        int half = q & 1, lo = q >> 1;
        #pragma unroll
        for (int g = 0; g < 4; g++) {
            unsigned short u8[8] __attribute__((aligned(16)));
            #pragma unroll
            for (int j = 0; j < 8; j++) {
                float f = -2.0f * v[half*32 + g*8 + j];   // exact scale
                unsigned short h = bf16_rne(f);
                if (lo) h = bf16_rne(f - __uint_as_float((unsigned)h << 16));
                u8[j] = h;
            }
            size_t off = (size_t)cc * 8192 + ct * 2048 + q * 512 + (g * 16 + cl) * 8;
            *(uint4*)(wsB + off) = *(const uint4*)u8;
        }
    }
}

// ---------------------------------------------------------------------------
// main (r20): single-variable probe on the r15 base (proven 42 us, VGPR 64).
// Chain model: per-tile critical path = load-wait + 6 chained MFMAs +
// min-update + TWO DEPENDENT __shfl_xor ds-ops (~120cy each, single-
// outstanding) + guarded atomic. The shfl pair (~240cy) exists only to
// pre-reduce 4 row-lanes before one atomic -- replace with a direct
// per-lane atomicMin(&scrE[kid], cm): fire-and-forget (no result read),
// so it leaves the dependent chain entirely. Cost: 4 contenders/address,
// ~4-way LDS serialization OFF the critical path (~15% LDS-pipe occupancy).
// Everything else identical to r15: 512 blocks x 512 thr, 8 waves =
// 4 row-groups x 2 code-halves, wave = 16 rows x 512 codes = 32 tiles,
// B straight from L2 (wsB 256 KB resident), acc init = cn4[col],
// B pre-scaled by -2 -> wv = acc[r].
// ---------------------------------------------------------------------------
__global__ __launch_bounds__(512, 4) void vq_main(
    const float* __restrict__ x, const float* __restrict__ cb,
    const unsigned short* __restrict__ wsB, const float* __restrict__ cn4,
    float* __restrict__ out, unsigned* __restrict__ minK,
    unsigned* __restrict__ counter, int* __restrict__ amb,
    float* __restrict__ gsumsq)
{
    __shared__ float    cn4L[1024];
    __shared__ unsigned scrE[1024];        // per-block per-code min full dist (raw bits)
    __shared__ float mD1[128], mD2[128];   // [row 0..63][half 0..1]
    __shared__ int   mI1[128];
    __shared__ int   tokS[64];
    __shared__ float redS[8];

    const int tid = threadIdx.x;
    const int lane = tid & 63;
    const int wi = tid >> 6;         // 0..7
    const int g = wi >> 1;           // row group 0..3 (16 rows each)
    const int h = wi & 1;            // code half: codes h*512 .. +511
    const int ln15 = lane & 15;
    const int q = lane >> 4;
    const int row0 = blockIdx.x * 64;

    // stage cn4 (1024 f32) + init scrE
    cn4L[tid]       = cn4[tid];
    cn4L[512 + tid] = cn4[512 + tid];
    scrE[tid]       = 0x7F800000u;
    scrE[512 + tid] = 0x7F800000u;

    // ---- A: 16 rows fp32 -> split-bf16 frags in regs; row norms via shfl ----
    bf16x8 Ah0, Ah1, Al0, Al1;
    float xnm4[4];
    {
        const float* xr = x + (size_t)(row0 + g*16 + ln15) * 64 + q * 8;
        float4 f0 = *(const float4*)xr;
        float4 f1 = *(const float4*)(xr + 4);
        float4 f2 = *(const float4*)(xr + 32);
        float4 f3 = *(const float4*)(xr + 36);
        float fa[8] = {f0.x,f0.y,f0.z,f0.w,f1.x,f1.y,f1.z,f1.w};
        float fb[8] = {f2.x,f2.y,f2.z,f2.w,f3.x,f3.y,f3.z,f3.w};
        unsigned short hh8[8] __attribute__((aligned(16)));
        unsigned short ll8[8] __attribute__((aligned(16)));
        unsigned short h28[8] __attribute__((aligned(16)));
        unsigned short l28[8] __attribute__((aligned(16)));
        float ss = 0.f;
        #pragma unroll
        for (int j = 0; j < 8; j++) {
            ss += fa[j]*fa[j] + fb[j]*fb[j];
            unsigned short hh = bf16_rne(fa[j]);
            hh8[j] = hh; ll8[j] = bf16_rne(fa[j] - __uint_as_float((unsigned)hh << 16));
            hh = bf16_rne(fb[j]);
            h28[j] = hh; l28[j] = bf16_rne(fb[j] - __uint_as_float((unsigned)hh << 16));
        }
        Ah0 = *(const bf16x8*)hh8; Al0 = *(const bf16x8*)ll8;
        Ah1 = *(const bf16x8*)h28; Al1 = *(const bf16x8*)l28;
        ss += __shfl_xor(ss, 16);
        ss += __shfl_xor(ss, 32);            // ||x_row(ln15)||^2
        #pragma unroll
        for (int r = 0; r < 4; r++)
            xnm4[r] = __shfl(ss, (q << 2) | r, 64) - 4.0f;  // xn(row q*4+r) - 4
    }
    __syncthreads();   // cn4L + scrE ready; the only barrier before the epilogue

    float d1[4], d2[4];
    int   i1[4];
    #pragma unroll
    for (int r = 0; r < 4; r++) { d1[r] = INFINITY; d2[r] = INFINITY; i1[r] = 0; }

    // ---- tile loop: 32 tiles of 16 codes, B straight from L2, no barriers ----
    // global tile tt = h*32+t -> byte offset tt*4096; frags at +0/1024/2048/3072
    const char* wsQ = (const char*)wsB + (size_t)h * 131072 + lane * 16;
    #pragma unroll 4
    for (int t = 0; t < 32; t++) {
        const char* tb = wsQ + t * 4096;
        bf16x8 Bh0 = *(const bf16x8*)(tb);
        bf16x8 Bh1 = *(const bf16x8*)(tb + 1024);
        bf16x8 Bl0 = *(const bf16x8*)(tb + 2048);
        bf16x8 Bl1 = *(const bf16x8*)(tb + 3072);
        const int kid = h*512 + t*16 + ln15;
        const float cn4v = cn4L[kid];           // per-column (code) bias
        f32x4 a0 = {cn4v, cn4v, cn4v, cn4v};
        // 6-product split emulation (hi.hi + hi.lo + lo.hi), B pre-scaled by -2:
        // acc = cn4 - 2*x.c
        a0 = __builtin_amdgcn_mfma_f32_16x16x32_bf16(Ah0, Bh0, a0, 0, 0, 0);
        a0 = __builtin_amdgcn_mfma_f32_16x16x32_bf16(Ah1, Bh1, a0, 0, 0, 0);
        a0 = __builtin_amdgcn_mfma_f32_16x16x32_bf16(Ah0, Bl0, a0, 0, 0, 0);
        a0 = __builtin_amdgcn_mfma_f32_16x16x32_bf16(Ah1, Bl1, a0, 0, 0, 0);
        a0 = __builtin_amdgcn_mfma_f32_16x16x32_bf16(Al0, Bh0, a0, 0, 0, 0);
        a0 = __builtin_amdgcn_mfma_f32_16x16x32_bf16(Al1, Bh1, a0, 0, 0, 0);
        float cm = INFINITY;
        #pragma unroll
        for (int r = 0; r < 4; r++) {
            float wv = a0[r];                   // row q*4+r, code kid
            // exact top-2: d2' = min(max(wv,d1),d2) (med3); d1' = min(wv,d1)
            d2[r] = fminf(fmaxf(wv, d1[r]), d2[r]);
            bool lt = wv < d1[r];
            i1[r] = lt ? kid : i1[r];
            d1[r] = fminf(wv, d1[r]);
            cm = fminf(cm, wv + xnm4[r]);       // full dist (entropy), lane's 4 rows
        }
        // fire-and-forget: no shfl pre-reduce, no result read -> off the
        // dependent chain. 4 contenders/address (rows q=0..3), LDS serializes.
        atomicMin(&scrE[kid], __float_as_uint(cm));
    }

    // ---- butterfly exact top-2 merge across the 16 code-column lanes ----
    #pragma unroll
    for (int d = 1; d < 16; d <<= 1) {
        #pragma unroll
        for (int r = 0; r < 4; r++) {
            float od1 = __shfl_xor(d1[r], d);
            int   oi1 = __shfl_xor(i1[r], d);
            float od2 = __shfl_xor(d2[r], d);
            bool take = (od1 < d1[r]) || (od1 == d1[r] && oi1 < i1[r]);
            float loser = take ? d1[r] : od1;
            d2[r] = fminf(fminf(d2[r], od2), loser);
            d1[r] = take ? od1 : d1[r];
            i1[r] = take ? oi1 : i1[r];
        }
    }
    if (ln15 == 0) {
        #pragma unroll
        for (int r = 0; r < 4; r++) {
            int idx = (g*16 + q*4 + r) * 2 + h;
            mD1[idx] = d1[r]; mI1[idx] = i1[r]; mD2[idx] = d2[r];
        }
    }
    __syncthreads();   // per-half candidates staged; all scrE atomics done

    // ---- exact cross-half merge -> token + ambiguity (1 thread/row) ----
    if (tid < 64) {
        float a1 = mD1[tid*2],   b1 = mD1[tid*2+1];
        int   ai = mI1[tid*2],   bi = mI1[tid*2+1];
        float a2 = mD2[tid*2],   b2 = mD2[tid*2+1];
        bool ta = (a1 < b1) || (a1 == b1 && ai < bi);
        float D1 = ta ? a1 : b1;
        int   I1 = ta ? ai : bi;
        float D2 = ta ? fminf(a2, b1) : fminf(b2, a1);
        tokS[tid] = I1;
        if (D2 - D1 < GAP_THRESH) {
            unsigned idx = atomicAdd(counter, 1u);
            if (idx < AMB_CAP) { amb[2*idx] = row0 + tid; amb[2*idx+1] = I1; }
        }
    }

    // ---- entropy: filtered global atomicMin ----
    {
        unsigned u0 = scrE[tid];
        if (u0 < minK[tid]) atomicMin(&minK[tid], u0);          // race benign: monotone
        unsigned u1 = scrE[512 + tid];
        if (u1 < minK[512 + tid]) atomicMin(&minK[512 + tid], u1);
    }
    __syncthreads();   // tokS ready

    // ---- emb gather + sumsq (512 threads x 2 float4 = 64 rows x 16) ----
    {
        float acc2 = 0.f;
        #pragma unroll
        for (int uu = 0; uu < 2; uu++) {
            int u = uu*512 + tid;
            int row = u >> 4, c4 = u & 15;
            int tok = tokS[row];
            float4 c = ((const float4*)(cb + (size_t)tok*64))[c4];
            float4 xx = ((const float4*)(x + (size_t)(row0 + row)*64))[c4];
            ((float4*)(out + (size_t)(row0 + row)*64))[c4] = c;
            float dx = c.x-xx.x, dy = c.y-xx.y, dz = c.z-xx.z, dw = c.w-xx.w;
            acc2 += dx*dx + dy*dy + dz*dz + dw*dw;
        }
        #pragma unroll
        for (int o = 32; o > 0; o >>= 1) acc2 += __shfl_down(acc2, o);
        if (lane == 0) redS[wi] = acc2;
        __syncthreads();
        if (tid == 0) {
            float t = 0.f;
            #pragma unroll
            for (int w = 0; w < 8; w++) t += redS[w];
            atomicAdd(gsumsq, t);
        }
    }
}

// ---------------------------------------------------------------------------
// tail: 64 blocks. (A) fp64 fixup with cb staged through LDS in 4 coalesced
// 64-KB batches. (B) last-ticket block: sum minK + loss. (unchanged)
// ---------------------------------------------------------------------------
__global__ __launch_bounds__(256) void vq_tail(
    const float* __restrict__ x, const float* __restrict__ cb,
    float* __restrict__ out, const unsigned* __restrict__ counter,
    const int* __restrict__ amb, float* __restrict__ gsumsq,
    unsigned* __restrict__ ticket, const unsigned* __restrict__ minK,
    float* __restrict__ out_loss)
{
    __shared__ __align__(16) float cbS[16384];   // 64 KB: 256 codes x 64 dims
    __shared__ double xs[64];
    __shared__ double bd[256];
    __shared__ int    bi[256];
    __shared__ unsigned lastS;
    __shared__ float redS[4];

    const int tid = threadIdx.x;

    // ---- A: fp64 re-decision for ambiguous rows (coalesced cb staging) ----
    unsigned cnt = *counter; if (cnt > AMB_CAP) cnt = AMB_CAP;
    for (unsigned i = blockIdx.x; i < cnt; i += gridDim.x) {
        int row = amb[2*i], oldk = amb[2*i+1];
        __syncthreads();
        if (tid < 64) xs[tid] = (double)x[(size_t)row*64 + tid];
        __syncthreads();
        double xn = 0.0;
        #pragma unroll 8
        for (int d = 0; d < 64; d++) xn += xs[d]*xs[d];
        double best = INFINITY; int bk = 1 << 30;
        for (int b = 0; b < 4; b++) {           // 256 codes per batch
            __syncthreads();                    // cbS free for reuse
            #pragma unroll
            for (int k = 0; k < 16; k++)        // 64 KB coalesced: 16 float4/thread
                ((float4*)cbS)[k*256 + tid] = ((const float4*)cb)[b*4096 + k*256 + tid];
            __syncthreads();
            int kcode = b*256 + tid;
            const int t6 = tid & 63;
            double dot = 0.0, cn2 = 0.0;
            #pragma unroll 8
            for (int dd = 0; dd < 64; dd++) {
                int d = (dd + t6) & 63;         // rotation: 2 lanes/bank (free)
                double cv = (double)cbS[tid*64 + d];
                dot = fma(xs[d], cv, dot);
                cn2 = fma(cv, cv, cn2);
            }
            double dist = (xn - 2.0*dot) + cn2;
            if (dist < best || (dist == best && kcode < bk)) { best = dist; bk = kcode; }
        }
        bd[tid] = best; bi[tid] = bk;
        __syncthreads();
        for (int s = 128; s > 0; s >>= 1) {
            if (tid < s) {
                double od = bd[tid+s]; int ok = bi[tid+s];
                if (od < bd[tid] || (od == bd[tid] && ok < bi[tid])) { bd[tid] = od; bi[tid] = ok; }
            }
            __syncthreads();
        }
        int bestk = bi[0];
        if (bestk != oldk) {
            double part = 0.0;
            if (tid < 64) {
                float cn = cb[(size_t)bestk*64 + tid];
                float co = cb[(size_t)oldk*64 + tid];
                out[(size_t)row*64 + tid] = cn;
                double dn = (double)cn - xs[tid];
                double dl = (double)co - xs[tid];
                part = dn*dn - dl*dl;
            }
            __syncthreads();
            bd[tid] = part;
            __syncthreads();
            for (int s = 128; s > 0; s >>= 1) {
                if (tid < s) bd[tid] += bd[tid+s];
                __syncthreads();
            }
            if (tid == 0) atomicAdd(gsumsq, (float)bd[0]);
        }
    }

    // ---- B: last block assembles the loss ----
    __syncthreads();
    if (tid == 0) {
        __threadfence();
        lastS = (atomicAdd(ticket, 1u) == 63u) ? 1u : 0u;
    }
    __syncthreads();
    if (lastS) {
        __threadfence();
        float s = 0.f;
        #pragma unroll
        for (int jj = 0; jj < 4; jj++)
            s += __uint_as_float(minK[jj*256 + tid]);   // raw bits of positive dists
        #pragma unroll
        for (int o = 32; o > 0; o >>= 1) s += __shfl_down(s, o);
        if ((tid & 63) == 0) redS[tid >> 6] = s;
        __syncthreads();
        if (tid == 0) {
            float gs = atomicAdd(gsumsq, 0.0f);         // coherent device-scope read
            float tot = redS[0] + redS[1] + redS[2] + redS[3];
            out_loss[0] = 1.25f * (gs / 2097152.0f) + 0.1f * (tot / 1024.0f);
        }
    }
}

extern "C" void kernel_launch(void* const* d_in, const int* in_sizes, int n_in,
                              void* d_out, int out_size, void* d_ws, size_t ws_size,
                              hipStream_t stream) {
    const float* x  = (const float*)d_in[0];   // [32768, 64]
    const float* cb = (const float*)d_in[1];   // [1024, 64]
    float* out = (float*)d_out;                // [0,2097152): emb; [2097152]: loss

    char* ws = (char*)d_ws;
    unsigned*       counter = (unsigned*)ws;                    // @0
    float*          gsumsq  = (float*)(ws + 4);                 // @4
    unsigned*       ticket  = (unsigned*)(ws + 8);              // @8
    float*          cn4     = (float*)(ws + 1024);              // 4 KB
    unsigned*       minK    = (unsigned*)(ws + 8192);           // 4 KB
    int*            amb     = (int*)(ws + 16384);               // 64 KB
    unsigned short* wsB     = (unsigned short*)(ws + 131072);   // 256 KB

    vq_prep<<<16,  64,  0, stream>>>(cb, cn4, minK, counter, gsumsq, ticket, wsB);
    vq_main<<<512, 512, 0, stream>>>(x, cb, wsB, cn4, out, minK, counter, amb, gsumsq);
    vq_tail<<<64,  256, 0, stream>>>(x, cb, out, counter, amb, gsumsq, ticket, minK,
                                     out + 2097152);
}